// Round 10
// baseline (248.521 us; speedup 1.0000x reference)
//
#include <hip/hip_runtime.h>
#include <math.h>

#define S_LEN 2048
#define NHEAD 16
#define HDIM  64

typedef __attribute__((ext_vector_type(8))) short bf16x8;
typedef __attribute__((ext_vector_type(4))) float f32x4;

__device__ __forceinline__ unsigned short f2bf(float f) {
    union { float f; unsigned u; } v; v.f = f;
    unsigned r = v.u + 0x7fffu + ((v.u >> 16) & 1u);
    return (unsigned short)(r >> 16);
}

// async 16B global->LDS. LDS dest must be wave-uniform base + lane*16.
__device__ __forceinline__ void gl2lds16(const void* g, void* l) {
    __builtin_amdgcn_global_load_lds(
        (__attribute__((address_space(1))) void*)(void*)(g),
        (__attribute__((address_space(3))) void*)(l), 16, 0, 0);
}

// =====================================================================
// Kernel 0: fused fp32->bf16 convert (blocks 0..8191) + RoPE table build
// (blocks 8192..8447). dst: hs[4M] | Wq[1M] | Wk[1M] | Wv[1M] | Wo[1M]
// =====================================================================
__global__ __launch_bounds__(256) void convert_kernel(
    const float* __restrict__ hs, const float* __restrict__ Wq,
    const float* __restrict__ Wk, const float* __restrict__ Wv,
    const float* __restrict__ Wo, unsigned short* __restrict__ dst,
    float2* __restrict__ rtab)
{
    const int bid = blockIdx.x;
    if (bid >= 8192) {
        const int gid = (bid - 8192) * 256 + threadIdx.x;   // 65536
        const int s = gid >> 5, i = gid & 31;
        const float l2c = 0.41524101186092029f;             // log2(10000)/32
        const float freq = exp2f(-(float)i * l2c);
        const float ang = (float)s * freq;
        float2 cs;
        cs.x = cosf(ang);
        cs.y = sinf(ang);
        rtab[gid] = cs;
        return;
    }
    const int gid = bid * 256 + threadIdx.x;
    const int n = gid << 2;
    const float* src; int off;
    if (n < (4 << 20))      { src = hs; off = n; }
    else if (n < (5 << 20)) { src = Wq; off = n - (4 << 20); }
    else if (n < (6 << 20)) { src = Wk; off = n - (5 << 20); }
    else if (n < (7 << 20)) { src = Wv; off = n - (6 << 20); }
    else                    { src = Wo; off = n - (7 << 20); }
    const float4 v = *(const float4*)(src + off);
    ushort4 o;
    o.x = f2bf(v.x); o.y = f2bf(v.y); o.z = f2bf(v.z); o.w = f2bf(v.w);
    *(ushort4*)(dst + n) = o;
}

// =====================================================================
// Kernel 1: QKV GEMM, bf16 MFMA 16x16x32, tile 128x128 BK=64, RoPE fused.
// tau row-permuted B staging packs each lane's 4 output columns:
//   Q/K: tau = 2*ln+(jt&1)+32*(jt>>1) -> RoPE pairs in-lane, 2x b32 stores
//   V:   tau = 4*ln+jt -> regs 0..3 = consecutive s at fixed hd:
//        writes TRANSPOSED Vt[bh][hd][s] b64 directly (vtrans kernel gone).
// =====================================================================
__global__ __launch_bounds__(256, 3) void qkv_gemm_kernel(
    const unsigned short* __restrict__ X,     // [4096][1024] bf16
    const unsigned short* __restrict__ Wall,  // wq|wk|wv (1M each)
    const float* __restrict__ bq, const float* __restrict__ bk,
    const float* __restrict__ bv, const float2* __restrict__ rtab,
    unsigned short* __restrict__ qo, unsigned short* __restrict__ ko,
    unsigned short* __restrict__ vt)
{
    __shared__ unsigned short As[128 * 64];
    __shared__ unsigned short Bs[128 * 64];

    const int mat = blockIdx.x >> 3;
    const int n0  = (blockIdx.x & 7) << 7;
    const int m0  = blockIdx.y << 7;
    const unsigned short* W = Wall + (mat << 20);
    const float* bias = (mat == 0) ? bq : (mat == 1) ? bk : bv;

    const int tid = threadIdx.x;
    const int wave = tid >> 6, lane = tid & 63;
    const int quad = lane >> 4, ln = lane & 15;
    const int wm = (wave >> 1) << 6, wn = (wave & 1) << 6;

    // hoisted staging pointers (tau row-permutation on B)
    const unsigned short* xptr[4];
    const unsigned short* wptr[4];
    #pragma unroll
    for (int L = 0; L < 4; ++L) {
        const int i = tid + (L << 8);
        const int r = i >> 3, cl = i & 7;
        const int cg = (cl ^ (r & 7)) << 3;
        const int rq = r & 63;
        const int tau = (mat < 2)
            ? ((r & 64) | ((rq & 15) << 1) | ((rq >> 4) & 1) | (((rq >> 5) & 1) << 5))
            : ((r & 64) | ((rq & 15) << 2) | (rq >> 4));
        xptr[L] = X + (m0 + r) * 1024 + cg;
        wptr[L] = W + (n0 + tau) * 1024 + cg;
    }

    f32x4 acc[4][4] = {};

    for (int k0 = 0; k0 < 1024; k0 += 64) {
        #pragma unroll
        for (int L = 0; L < 4; ++L) {
            const int i = tid + (L << 8);
            gl2lds16(xptr[L] + k0, &As[i << 3]);
            gl2lds16(wptr[L] + k0, &Bs[i << 3]);
        }
        __syncthreads();
        #pragma unroll
        for (int s = 0; s < 2; ++s) {
            bf16x8 a[4], b[4];
            #pragma unroll
            for (int t = 0; t < 4; ++t) {
                const int ra = wm + (t << 4) + ln;
                a[t] = *(const bf16x8*)&As[(ra << 6) + ((((s << 2) | quad) ^ (ra & 7)) << 3)];
                const int rb = wn + (t << 4) + ln;
                b[t] = *(const bf16x8*)&Bs[(rb << 6) + ((((s << 2) | quad) ^ (rb & 7)) << 3)];
            }
            #pragma unroll
            for (int i = 0; i < 4; ++i)
                #pragma unroll
                for (int j = 0; j < 4; ++j)
                    acc[i][j] = __builtin_amdgcn_mfma_f32_16x16x32_bf16(a[i], b[j], acc[i][j], 0, 0, 0);
        }
        __syncthreads();
    }

    const int h = (n0 + wn) >> 6;

    if (mat < 2) {
        unsigned short* out = (mat == 0) ? qo : ko;
        const int nb = n0 + wn + (ln << 1);
        const float b0 = bias[nb],      b1 = bias[nb + 1];
        const float b2 = bias[nb + 32], b3 = bias[nb + 33];
        #pragma unroll
        for (int i = 0; i < 4; ++i) {
            #pragma unroll
            for (int reg = 0; reg < 4; ++reg) {
                const int m = m0 + wm + (i << 4) + (quad << 2) + reg;
                const int b_ = m >> 11, s_ = m & 2047;
                unsigned short* o = out + ((((b_ << 4) + h) << 11) + s_) * 64;
                const float4 cs = *(const float4*)(rtab + (s_ << 5) + (ln << 1));
                const float x1a = acc[i][0][reg] + b0, x1b = acc[i][1][reg] + b1;
                const float x2a = acc[i][2][reg] + b2, x2b = acc[i][3][reg] + b3;
                const float r0a = x1a * cs.x - x2a * cs.y;
                const float r0b = x1b * cs.z - x2b * cs.w;
                const float r1a = x2a * cs.x + x1a * cs.y;
                const float r1b = x2b * cs.z + x1b * cs.w;
                const unsigned ua = __float_as_uint(r0a) + 0x8000u;
                const unsigned ub = __float_as_uint(r0b) + 0x8000u;
                const unsigned uc = __float_as_uint(r1a) + 0x8000u;
                const unsigned ud = __float_as_uint(r1b) + 0x8000u;
                *(unsigned*)(o + (ln << 1))      = __builtin_amdgcn_perm(ub, ua, 0x07060302u);
                *(unsigned*)(o + 32 + (ln << 1)) = __builtin_amdgcn_perm(ud, uc, 0x07060302u);
            }
        }
    } else {
        // V: write transposed Vt[bh][hd][s], regs = 4 consecutive s
        const float4 bv4 = *(const float4*)(bias + n0 + wn + (ln << 2));
        const float bvv[4] = {bv4.x, bv4.y, bv4.z, bv4.w};
        #pragma unroll
        for (int i = 0; i < 4; ++i) {
            const int m = m0 + wm + (i << 4) + (quad << 2);   // reg=0 row
            const int b_ = m >> 11, s_ = m & 2047;
            const int bh = (b_ << 4) + h;
            #pragma unroll
            for (int jt = 0; jt < 4; ++jt) {
                const int hd = (ln << 2) + jt;
                const unsigned ua = __float_as_uint(acc[i][jt][0] + bvv[jt]) + 0x8000u;
                const unsigned ub = __float_as_uint(acc[i][jt][1] + bvv[jt]) + 0x8000u;
                const unsigned uc = __float_as_uint(acc[i][jt][2] + bvv[jt]) + 0x8000u;
                const unsigned ud = __float_as_uint(acc[i][jt][3] + bvv[jt]) + 0x8000u;
                uint2 w;
                w.x = __builtin_amdgcn_perm(ub, ua, 0x07060302u);
                w.y = __builtin_amdgcn_perm(ud, uc, 0x07060302u);
                *(uint2*)(vt + (((size_t)((bh << 6) + hd)) << 11) + s_) = w;
            }
        }
    }
}

// =====================================================================
// Kernel 3: flash v7 — cross-iteration P pipeline (P double-buffered):
//   iter kt: PV(kt-1) first (pre-barrier, reads Ps/Vt of kt-1);
//            barrier; stage kt+1 into freed buffers; QK(kt); exp;
//            write P[kt&1]. Drain PV(31) after the loop.
//   Removes the intra-iteration LDS write->read serialization chain.
//   Buffer lifetimes verified: Vt[kt-1] read pre-barrier at iter kt,
//   overwritten post-barrier same iter; Ks[kt] read post-barrier iter kt,
//   overwritten post-barrier iter kt+1. One barrier per iter.
// LDS 48KB -> 3 blocks/CU (== measured occupancy at 40KB, no loss).
// Block order idx = bh*32+qt (mask-tile XCD locality; R4: 5x FETCH if not).
// =====================================================================
__global__ __launch_bounds__(256, 3) void flash_kernel(
    const unsigned short* __restrict__ qb, const unsigned short* __restrict__ kb,
    const unsigned short* __restrict__ vtb, const float* __restrict__ mask,
    unsigned short* __restrict__ attn)
{
    __shared__ unsigned short Ks[2][64 * 64];
    __shared__ unsigned short Vt[2][64 * 64];
    __shared__ unsigned short Ps[2][64 * 64];

    const int qt = blockIdx.x & 31;
    const int bh = blockIdx.x >> 5;
    const int b_ = bh >> 4, h = bh & 15;
    const int q0 = qt << 6;

    const int tid = threadIdx.x;
    const int wave = tid >> 6, lane = tid & 63;
    const int quad = lane >> 4, ln = lane & 15;

    const unsigned short* qrow = qb + ((size_t)((bh << 11) + q0 + (wave << 4) + ln) << 6);
    bf16x8 qa[2];
    qa[0] = *(const bf16x8*)(qrow + (quad << 3));
    qa[1] = *(const bf16x8*)(qrow + 32 + (quad << 3));

    const float scale = 0.125f / logf(2048.0f);

    const float* mbase = mask + ((size_t)b_ << 22)
                       + ((size_t)(q0 + (wave << 4) + (quad << 2)) << 11) + (ln << 2);

    unsigned short* Pw0 = Ps[0] + (wave << 10);
    unsigned short* Pw1 = Ps[1] + (wave << 10);

    const int i0 = tid, i1 = tid + 256;
    const int r0 = i0 >> 3, c0 = ((i0 & 7) ^ (r0 & 7)) << 3;
    const int r1 = i1 >> 3, c1 = ((i1 & 7) ^ (r1 & 7)) << 3;
    const int p0 = ((r0 & 15) << 2) + (r0 >> 4);
    const int p1 = ((r1 & 15) << 2) + (r1 >> 4);
    const unsigned short* kg0 = kb + ((bh << 11) + p0) * 64 + c0;
    const unsigned short* kg1 = kb + ((bh << 11) + p1) * 64 + c1;
    const unsigned short* vg0 = vtb + ((bh << 6) + r0) * 2048 + c0;
    const unsigned short* vg1 = vtb + ((bh << 6) + r1) * 2048 + c1;

    float l_i[4] = {0.f, 0.f, 0.f, 0.f};
    f32x4 O[4] = {};

    // prologue: stage tile 0 -> buf0, mask[0] -> mcur
    gl2lds16(kg0, &Ks[0][i0 << 3]);
    gl2lds16(kg1, &Ks[0][i1 << 3]);
    gl2lds16(vg0, &Vt[0][i0 << 3]);
    gl2lds16(vg1, &Vt[0][i1 << 3]);
    float4 mcur[4];
    #pragma unroll
    for (int reg = 0; reg < 4; ++reg)
        mcur[reg] = *(const float4*)(mbase + (reg << 11));

    for (int kt = 0; kt < 32; ++kt) {
        const int cur = kt & 1;

        // PV(kt-1): A = P[cur^1] (wave-private), B = Vt[cur^1]
        if (kt > 0) {
            const unsigned short* Pp = cur ? Pw0 : Pw1;
            #pragma unroll
            for (int s = 0; s < 2; ++s) {
                const bf16x8 a = *(const bf16x8*)&Pp[(ln << 6) + ((((s << 2) | quad) ^ (ln & 7)) << 3)];
                bf16x8 bfr[4];
                #pragma unroll
                for (int j = 0; j < 4; ++j) {
                    const int r = (j << 4) + ln;
                    bfr[j] = *(const bf16x8*)&Vt[cur ^ 1][(r << 6) + ((((s << 2) | quad) ^ (r & 7)) << 3)];
                }
                #pragma unroll
                for (int j = 0; j < 4; ++j)
                    O[j] = __builtin_amdgcn_mfma_f32_16x16x32_bf16(a, bfr[j], O[j], 0, 0, 0);
            }
        }

        __syncthreads();   // tile kt staged; Vt[cur^1]/Ks[cur^1] now free

        float4 mnext[4];
        if (kt < 31) {
            const int kn = (kt + 1) << 6;
            gl2lds16(kg0 + (kn << 6), &Ks[cur ^ 1][i0 << 3]);
            gl2lds16(kg1 + (kn << 6), &Ks[cur ^ 1][i1 << 3]);
            gl2lds16(vg0 + kn, &Vt[cur ^ 1][i0 << 3]);
            gl2lds16(vg1 + kn, &Vt[cur ^ 1][i1 << 3]);
            #pragma unroll
            for (int reg = 0; reg < 4; ++reg)
                mnext[reg] = *(const float4*)(mbase + kn + (reg << 11));
        }

        // S = Q K^T (K rows pi-permuted: S col (j,ln) == orig k 4*ln+j)
        f32x4 sacc[4] = {};
        #pragma unroll
        for (int s = 0; s < 2; ++s) {
            bf16x8 bfr[4];
            #pragma unroll
            for (int j = 0; j < 4; ++j) {
                const int r = (j << 4) + ln;
                bfr[j] = *(const bf16x8*)&Ks[cur][(r << 6) + ((((s << 2) | quad) ^ (r & 7)) << 3)];
            }
            #pragma unroll
            for (int j = 0; j < 4; ++j)
                sacc[j] = __builtin_amdgcn_mfma_f32_16x16x32_bf16(qa[s], bfr[j], sacc[j], 0, 0, 0);
        }

        // softmax (m==0 fixed shift) + packed P write into Ps[cur]
        unsigned short* Pw = cur ? Pw1 : Pw0;
        #pragma unroll
        for (int reg = 0; reg < 4; ++reg) {
            const int pr = (quad << 2) + reg;
            const float m0f = mcur[reg].x, m1f = mcur[reg].y,
                        m2f = mcur[reg].z, m3f = mcur[reg].w;
            float p[4];
            p[0] = __expf(fmaf(sacc[0][reg], scale, m0f));
            p[1] = __expf(fmaf(sacc[1][reg], scale, m1f));
            p[2] = __expf(fmaf(sacc[2][reg], scale, m2f));
            p[3] = __expf(fmaf(sacc[3][reg], scale, m3f));
            l_i[reg] += (p[0] + p[1]) + (p[2] + p[3]);
            unsigned u0 = __float_as_uint(p[0]) + 0x8000u;
            unsigned u1 = __float_as_uint(p[1]) + 0x8000u;
            unsigned u2 = __float_as_uint(p[2]) + 0x8000u;
            unsigned u3 = __float_as_uint(p[3]) + 0x8000u;
            uint2 w;
            w.x = __builtin_amdgcn_perm(u1, u0, 0x07060302u);
            w.y = __builtin_amdgcn_perm(u3, u2, 0x07060302u);
            const int e = (pr << 6) + ((((ln >> 1) ^ (pr & 7)) << 3)) + ((ln & 1) << 2);
            *(uint2*)&Pw[e] = w;
        }

        if (kt < 31) {
            #pragma unroll
            for (int reg = 0; reg < 4; ++reg)
                mcur[reg] = mnext[reg];
        }
    }

    // drain: PV(31) from Ps[1], Vt[1]
    #pragma unroll
    for (int s = 0; s < 2; ++s) {
        const bf16x8 a = *(const bf16x8*)&Pw1[(ln << 6) + ((((s << 2) | quad) ^ (ln & 7)) << 3)];
        bf16x8 bfr[4];
        #pragma unroll
        for (int j = 0; j < 4; ++j) {
            const int r = (j << 4) + ln;
            bfr[j] = *(const bf16x8*)&Vt[1][(r << 6) + ((((s << 2) | quad) ^ (r & 7)) << 3)];
        }
        #pragma unroll
        for (int j = 0; j < 4; ++j)
            O[j] = __builtin_amdgcn_mfma_f32_16x16x32_bf16(a, bfr[j], O[j], 0, 0, 0);
    }

    #pragma unroll
    for (int reg = 0; reg < 4; ++reg) {
        float l = l_i[reg];
        l += __shfl_xor(l, 1);
        l += __shfl_xor(l, 2);
        l += __shfl_xor(l, 4);
        l += __shfl_xor(l, 8);
        const float inv = 1.0f / l;
        const int qr = q0 + (wave << 4) + (quad << 2) + reg;
        unsigned short* op = attn + (((size_t)((b_ << 11) + qr)) << 10) + (h << 6);
        #pragma unroll
        for (int j = 0; j < 4; ++j)
            op[(j << 4) + ln] = f2bf(O[j][reg] * inv);
    }
}

// =====================================================================
// Kernel 4: out = attn @ Wo^T + bo, bf16 MFMA, fp32 out.
// tau-permuted Wo staging -> float4 stores + float4 bias.
// =====================================================================
__global__ __launch_bounds__(256, 3) void out_gemm_kernel(
    const unsigned short* __restrict__ X, const unsigned short* __restrict__ W,
    const float* __restrict__ bias, float* __restrict__ out)
{
    __shared__ unsigned short As[128 * 64];
    __shared__ unsigned short Bs[128 * 64];

    const int n0 = blockIdx.x << 7;
    const int m0 = blockIdx.y << 7;
    const int tid = threadIdx.x;
    const int wave = tid >> 6, lane = tid & 63;
    const int quad = lane >> 4, ln = lane & 15;
    const int wm = (wave >> 1) << 6, wn = (wave & 1) << 6;

    const unsigned short* xptr[4];
    const unsigned short* wptr[4];
    #pragma unroll
    for (int L = 0; L < 4; ++L) {
        const int i = tid + (L << 8);
        const int r = i >> 3, cl = i & 7;
        const int cg = (cl ^ (r & 7)) << 3;
        const int rq = r & 63;
        const int tau = (r & 64) | ((rq & 15) << 2) | (rq >> 4);
        xptr[L] = X + (m0 + r) * 1024 + cg;
        wptr[L] = W + (n0 + tau) * 1024 + cg;
    }

    f32x4 acc[4][4] = {};

    for (int k0 = 0; k0 < 1024; k0 += 64) {
        #pragma unroll
        for (int L = 0; L < 4; ++L) {
            const int i = tid + (L << 8);
            gl2lds16(xptr[L] + k0, &As[i << 3]);
            gl2lds16(wptr[L] + k0, &Bs[i << 3]);
        }
        __syncthreads();
        #pragma unroll
        for (int s = 0; s < 2; ++s) {
            bf16x8 a[4], b[4];
            #pragma unroll
            for (int t = 0; t < 4; ++t) {
                const int ra = wm + (t << 4) + ln;
                a[t] = *(const bf16x8*)&As[(ra << 6) + ((((s << 2) | quad) ^ (ra & 7)) << 3)];
                const int rb = wn + (t << 4) + ln;
                b[t] = *(const bf16x8*)&Bs[(rb << 6) + ((((s << 2) | quad) ^ (rb & 7)) << 3)];
            }
            #pragma unroll
            for (int i = 0; i < 4; ++i)
                #pragma unroll
                for (int j = 0; j < 4; ++j)
                    acc[i][j] = __builtin_amdgcn_mfma_f32_16x16x32_bf16(a[i], b[j], acc[i][j], 0, 0, 0);
        }
        __syncthreads();
    }

    const float4 bv4 = *(const float4*)(bias + n0 + wn + (ln << 2));

    #pragma unroll
    for (int i = 0; i < 4; ++i)
        #pragma unroll
        for (int reg = 0; reg < 4; ++reg) {
            const int m = m0 + wm + (i << 4) + (quad << 2) + reg;
            float4 ov;
            ov.x = acc[i][0][reg] + bv4.x;
            ov.y = acc[i][1][reg] + bv4.y;
            ov.z = acc[i][2][reg] + bv4.z;
            ov.w = acc[i][3][reg] + bv4.w;
            *(float4*)(out + m * 1024 + n0 + wn + (ln << 2)) = ov;
        }
}

// =====================================================================
extern "C" void kernel_launch(void* const* d_in, const int* in_sizes, int n_in,
                              void* d_out, int out_size, void* d_ws, size_t ws_size,
                              hipStream_t stream)
{
    const float* hs   = (const float*)d_in[0];
    const float* mask = (const float*)d_in[1];
    const float* Wq   = (const float*)d_in[2];
    const float* bq   = (const float*)d_in[3];
    const float* Wk   = (const float*)d_in[4];
    const float* bk   = (const float*)d_in[5];
    const float* Wv   = (const float*)d_in[6];
    const float* bv   = (const float*)d_in[7];
    const float* Wo   = (const float*)d_in[8];
    const float* bo   = (const float*)d_in[9];

    unsigned short* ws = (unsigned short*)d_ws;
    const size_t M1 = (size_t)1 << 20;
    unsigned short* hsb   = ws;              // 4M
    unsigned short* wall  = ws + 4 * M1;     // wq|wk|wv
    unsigned short* wob   = ws + 7 * M1;
    unsigned short* qbf   = ws + 8 * M1;
    unsigned short* kbf   = ws + 12 * M1;
    unsigned short* vtb   = ws + 16 * M1;
    unsigned short* attnb = ws + 20 * M1;
    float2*         rtab  = (float2*)(ws + 24 * M1);   // 512KB

    convert_kernel<<<8448, 256, 0, stream>>>(hs, Wq, Wk, Wv, Wo, ws, rtab);
    qkv_gemm_kernel<<<dim3(24, 32), 256, 0, stream>>>(hsb, wall, bq, bk, bv, rtab, qbf, kbf, vtb);
    flash_kernel<<<1024, 256, 0, stream>>>(qbf, kbf, vtb, mask, attnb);
    out_gemm_kernel<<<dim3(8, 32), 256, 0, stream>>>(attnb, wob, bo, (float*)d_out);
}

// Round 11
// 228.995 us; speedup vs baseline: 1.0853x; 1.0853x over previous
//
#include <hip/hip_runtime.h>
#include <math.h>

#define S_LEN 2048
#define NHEAD 16
#define HDIM  64

typedef __attribute__((ext_vector_type(8))) short bf16x8;
typedef __attribute__((ext_vector_type(4))) float f32x4;

__device__ __forceinline__ unsigned short f2bf(float f) {
    union { float f; unsigned u; } v; v.f = f;
    unsigned r = v.u + 0x7fffu + ((v.u >> 16) & 1u);
    return (unsigned short)(r >> 16);
}

// async 16B global->LDS. LDS dest must be wave-uniform base + lane*16.
__device__ __forceinline__ void gl2lds16(const void* g, void* l) {
    __builtin_amdgcn_global_load_lds(
        (__attribute__((address_space(1))) void*)(void*)(g),
        (__attribute__((address_space(3))) void*)(l), 16, 0, 0);
}

// =====================================================================
// Kernel 0: fused fp32->bf16 convert (blocks 0..8191) + RoPE table build
// (blocks 8192..8447). dst: hs[4M] | Wq[1M] | Wk[1M] | Wv[1M] | Wo[1M]
// =====================================================================
__global__ __launch_bounds__(256) void convert_kernel(
    const float* __restrict__ hs, const float* __restrict__ Wq,
    const float* __restrict__ Wk, const float* __restrict__ Wv,
    const float* __restrict__ Wo, unsigned short* __restrict__ dst,
    float2* __restrict__ rtab)
{
    const int bid = blockIdx.x;
    if (bid >= 8192) {
        const int gid = (bid - 8192) * 256 + threadIdx.x;   // 65536
        const int s = gid >> 5, i = gid & 31;
        const float l2c = 0.41524101186092029f;             // log2(10000)/32
        const float freq = exp2f(-(float)i * l2c);
        const float ang = (float)s * freq;
        float2 cs;
        cs.x = cosf(ang);
        cs.y = sinf(ang);
        rtab[gid] = cs;
        return;
    }
    const int gid = bid * 256 + threadIdx.x;
    const int n = gid << 2;
    const float* src; int off;
    if (n < (4 << 20))      { src = hs; off = n; }
    else if (n < (5 << 20)) { src = Wq; off = n - (4 << 20); }
    else if (n < (6 << 20)) { src = Wk; off = n - (5 << 20); }
    else if (n < (7 << 20)) { src = Wv; off = n - (6 << 20); }
    else                    { src = Wo; off = n - (7 << 20); }
    const float4 v = *(const float4*)(src + off);
    ushort4 o;
    o.x = f2bf(v.x); o.y = f2bf(v.y); o.z = f2bf(v.z); o.w = f2bf(v.w);
    *(ushort4*)(dst + n) = o;
}

// =====================================================================
// Kernel 1: QKV GEMM, bf16 MFMA 16x16x32, tile 128x128 BK=64, RoPE fused.
// tau row-permuted B staging packs each lane's 4 output columns:
//   Q/K: tau = 2*ln+(jt&1)+32*(jt>>1) -> RoPE pairs in-lane, 2x b32 stores
//   V:   tau = 4*ln+jt -> regs 0..3 = consecutive s at fixed hd:
//        writes TRANSPOSED Vt[bh][hd][s] b64 directly (no vtrans kernel).
// =====================================================================
__global__ __launch_bounds__(256, 3) void qkv_gemm_kernel(
    const unsigned short* __restrict__ X,     // [4096][1024] bf16
    const unsigned short* __restrict__ Wall,  // wq|wk|wv (1M each)
    const float* __restrict__ bq, const float* __restrict__ bk,
    const float* __restrict__ bv, const float2* __restrict__ rtab,
    unsigned short* __restrict__ qo, unsigned short* __restrict__ ko,
    unsigned short* __restrict__ vt)
{
    __shared__ unsigned short As[128 * 64];
    __shared__ unsigned short Bs[128 * 64];

    const int mat = blockIdx.x >> 3;
    const int n0  = (blockIdx.x & 7) << 7;
    const int m0  = blockIdx.y << 7;
    const unsigned short* W = Wall + (mat << 20);
    const float* bias = (mat == 0) ? bq : (mat == 1) ? bk : bv;

    const int tid = threadIdx.x;
    const int wave = tid >> 6, lane = tid & 63;
    const int quad = lane >> 4, ln = lane & 15;
    const int wm = (wave >> 1) << 6, wn = (wave & 1) << 6;

    // hoisted staging pointers (tau row-permutation on B)
    const unsigned short* xptr[4];
    const unsigned short* wptr[4];
    #pragma unroll
    for (int L = 0; L < 4; ++L) {
        const int i = tid + (L << 8);
        const int r = i >> 3, cl = i & 7;
        const int cg = (cl ^ (r & 7)) << 3;
        const int rq = r & 63;
        const int tau = (mat < 2)
            ? ((r & 64) | ((rq & 15) << 1) | ((rq >> 4) & 1) | (((rq >> 5) & 1) << 5))
            : ((r & 64) | ((rq & 15) << 2) | (rq >> 4));
        xptr[L] = X + (m0 + r) * 1024 + cg;
        wptr[L] = W + (n0 + tau) * 1024 + cg;
    }

    f32x4 acc[4][4] = {};

    for (int k0 = 0; k0 < 1024; k0 += 64) {
        #pragma unroll
        for (int L = 0; L < 4; ++L) {
            const int i = tid + (L << 8);
            gl2lds16(xptr[L] + k0, &As[i << 3]);
            gl2lds16(wptr[L] + k0, &Bs[i << 3]);
        }
        __syncthreads();
        #pragma unroll
        for (int s = 0; s < 2; ++s) {
            bf16x8 a[4], b[4];
            #pragma unroll
            for (int t = 0; t < 4; ++t) {
                const int ra = wm + (t << 4) + ln;
                a[t] = *(const bf16x8*)&As[(ra << 6) + ((((s << 2) | quad) ^ (ra & 7)) << 3)];
                const int rb = wn + (t << 4) + ln;
                b[t] = *(const bf16x8*)&Bs[(rb << 6) + ((((s << 2) | quad) ^ (rb & 7)) << 3)];
            }
            #pragma unroll
            for (int i = 0; i < 4; ++i)
                #pragma unroll
                for (int j = 0; j < 4; ++j)
                    acc[i][j] = __builtin_amdgcn_mfma_f32_16x16x32_bf16(a[i], b[j], acc[i][j], 0, 0, 0);
        }
        __syncthreads();
    }

    const int h = (n0 + wn) >> 6;

    if (mat < 2) {
        unsigned short* out = (mat == 0) ? qo : ko;
        const int nb = n0 + wn + (ln << 1);
        const float b0 = bias[nb],      b1 = bias[nb + 1];
        const float b2 = bias[nb + 32], b3 = bias[nb + 33];
        #pragma unroll
        for (int i = 0; i < 4; ++i) {
            #pragma unroll
            for (int reg = 0; reg < 4; ++reg) {
                const int m = m0 + wm + (i << 4) + (quad << 2) + reg;
                const int b_ = m >> 11, s_ = m & 2047;
                unsigned short* o = out + ((((b_ << 4) + h) << 11) + s_) * 64;
                const float4 cs = *(const float4*)(rtab + (s_ << 5) + (ln << 1));
                const float x1a = acc[i][0][reg] + b0, x1b = acc[i][1][reg] + b1;
                const float x2a = acc[i][2][reg] + b2, x2b = acc[i][3][reg] + b3;
                const float r0a = x1a * cs.x - x2a * cs.y;
                const float r0b = x1b * cs.z - x2b * cs.w;
                const float r1a = x2a * cs.x + x1a * cs.y;
                const float r1b = x2b * cs.z + x1b * cs.w;
                const unsigned ua = __float_as_uint(r0a) + 0x8000u;
                const unsigned ub = __float_as_uint(r0b) + 0x8000u;
                const unsigned uc = __float_as_uint(r1a) + 0x8000u;
                const unsigned ud = __float_as_uint(r1b) + 0x8000u;
                *(unsigned*)(o + (ln << 1))      = __builtin_amdgcn_perm(ub, ua, 0x07060302u);
                *(unsigned*)(o + 32 + (ln << 1)) = __builtin_amdgcn_perm(ud, uc, 0x07060302u);
            }
        }
    } else {
        // V: write transposed Vt[bh][hd][s], regs = 4 consecutive s
        const float4 bv4 = *(const float4*)(bias + n0 + wn + (ln << 2));
        const float bvv[4] = {bv4.x, bv4.y, bv4.z, bv4.w};
        #pragma unroll
        for (int i = 0; i < 4; ++i) {
            const int m = m0 + wm + (i << 4) + (quad << 2);   // reg=0 row
            const int b_ = m >> 11, s_ = m & 2047;
            const int bh = (b_ << 4) + h;
            #pragma unroll
            for (int jt = 0; jt < 4; ++jt) {
                const int hd = (ln << 2) + jt;
                const unsigned ua = __float_as_uint(acc[i][jt][0] + bvv[jt]) + 0x8000u;
                const unsigned ub = __float_as_uint(acc[i][jt][1] + bvv[jt]) + 0x8000u;
                const unsigned uc = __float_as_uint(acc[i][jt][2] + bvv[jt]) + 0x8000u;
                const unsigned ud = __float_as_uint(acc[i][jt][3] + bvv[jt]) + 0x8000u;
                uint2 w;
                w.x = __builtin_amdgcn_perm(ub, ua, 0x07060302u);
                w.y = __builtin_amdgcn_perm(ud, uc, 0x07060302u);
                *(uint2*)(vt + (((size_t)((bh << 6) + hd)) << 11) + s_) = w;
            }
        }
    }
}

// =====================================================================
// Kernel 3: flash v8 — cross-iteration P pipeline with SINGLE P buffer.
// Ps is wave-private: within one wave LDS ops are program-ordered, so at
// iter kt the wave reads Pw (holding P(kt-1)) for PV, then overwrites it
// with P(kt) — the WAR wait is hidden by barrier+staging+QK in between.
//   iter kt: PV(kt-1) pre-barrier (Vt[cur^1]); barrier; stage kt+1;
//            QK(kt); exp; write Pw. Drain PV(31) after loop.
// LDS = 2x(Ks+Vt) 32KB + Ps 8KB = 40KB -> 4 blocks/CU (grid-matched;
// R10 proved 48KB costs 25% wall via the 3+1 tail).
// Block order idx = bh*32+qt (mask-tile XCD locality; R4: 5x FETCH if not).
// =====================================================================
__global__ __launch_bounds__(256, 4) void flash_kernel(
    const unsigned short* __restrict__ qb, const unsigned short* __restrict__ kb,
    const unsigned short* __restrict__ vtb, const float* __restrict__ mask,
    unsigned short* __restrict__ attn)
{
    __shared__ unsigned short Ks[2][64 * 64];
    __shared__ unsigned short Vt[2][64 * 64];
    __shared__ unsigned short Ps[64 * 64];

    const int qt = blockIdx.x & 31;
    const int bh = blockIdx.x >> 5;
    const int b_ = bh >> 4, h = bh & 15;
    const int q0 = qt << 6;

    const int tid = threadIdx.x;
    const int wave = tid >> 6, lane = tid & 63;
    const int quad = lane >> 4, ln = lane & 15;

    const unsigned short* qrow = qb + ((size_t)((bh << 11) + q0 + (wave << 4) + ln) << 6);
    bf16x8 qa[2];
    qa[0] = *(const bf16x8*)(qrow + (quad << 3));
    qa[1] = *(const bf16x8*)(qrow + 32 + (quad << 3));

    const float scale = 0.125f / logf(2048.0f);

    const float* mbase = mask + ((size_t)b_ << 22)
                       + ((size_t)(q0 + (wave << 4) + (quad << 2)) << 11) + (ln << 2);

    unsigned short* Pw = Ps + (wave << 10);

    const int i0 = tid, i1 = tid + 256;
    const int r0 = i0 >> 3, c0 = ((i0 & 7) ^ (r0 & 7)) << 3;
    const int r1 = i1 >> 3, c1 = ((i1 & 7) ^ (r1 & 7)) << 3;
    const int p0 = ((r0 & 15) << 2) + (r0 >> 4);
    const int p1 = ((r1 & 15) << 2) + (r1 >> 4);
    const unsigned short* kg0 = kb + ((bh << 11) + p0) * 64 + c0;
    const unsigned short* kg1 = kb + ((bh << 11) + p1) * 64 + c1;
    const unsigned short* vg0 = vtb + ((bh << 6) + r0) * 2048 + c0;
    const unsigned short* vg1 = vtb + ((bh << 6) + r1) * 2048 + c1;

    float l_i[4] = {0.f, 0.f, 0.f, 0.f};
    f32x4 O[4] = {};

    // prologue: stage tile 0 -> buf0, mask[0] -> mcur
    gl2lds16(kg0, &Ks[0][i0 << 3]);
    gl2lds16(kg1, &Ks[0][i1 << 3]);
    gl2lds16(vg0, &Vt[0][i0 << 3]);
    gl2lds16(vg1, &Vt[0][i1 << 3]);
    float4 mcur[4];
    #pragma unroll
    for (int reg = 0; reg < 4; ++reg)
        mcur[reg] = *(const float4*)(mbase + (reg << 11));

    for (int kt = 0; kt < 32; ++kt) {
        const int cur = kt & 1;

        // PV(kt-1): A = Pw (holds P(kt-1), wave-private), B = Vt[cur^1]
        if (kt > 0) {
            #pragma unroll
            for (int s = 0; s < 2; ++s) {
                const bf16x8 a = *(const bf16x8*)&Pw[(ln << 6) + ((((s << 2) | quad) ^ (ln & 7)) << 3)];
                bf16x8 bfr[4];
                #pragma unroll
                for (int j = 0; j < 4; ++j) {
                    const int r = (j << 4) + ln;
                    bfr[j] = *(const bf16x8*)&Vt[cur ^ 1][(r << 6) + ((((s << 2) | quad) ^ (r & 7)) << 3)];
                }
                #pragma unroll
                for (int j = 0; j < 4; ++j)
                    O[j] = __builtin_amdgcn_mfma_f32_16x16x32_bf16(a, bfr[j], O[j], 0, 0, 0);
            }
        }

        __syncthreads();   // tile kt staged; Vt[cur^1]/Ks[cur^1] now free

        float4 mnext[4];
        if (kt < 31) {
            const int kn = (kt + 1) << 6;
            gl2lds16(kg0 + (kn << 6), &Ks[cur ^ 1][i0 << 3]);
            gl2lds16(kg1 + (kn << 6), &Ks[cur ^ 1][i1 << 3]);
            gl2lds16(vg0 + kn, &Vt[cur ^ 1][i0 << 3]);
            gl2lds16(vg1 + kn, &Vt[cur ^ 1][i1 << 3]);
            #pragma unroll
            for (int reg = 0; reg < 4; ++reg)
                mnext[reg] = *(const float4*)(mbase + kn + (reg << 11));
        }

        // S = Q K^T (K rows pi-permuted: S col (j,ln) == orig k 4*ln+j)
        f32x4 sacc[4] = {};
        #pragma unroll
        for (int s = 0; s < 2; ++s) {
            bf16x8 bfr[4];
            #pragma unroll
            for (int j = 0; j < 4; ++j) {
                const int r = (j << 4) + ln;
                bfr[j] = *(const bf16x8*)&Ks[cur][(r << 6) + ((((s << 2) | quad) ^ (r & 7)) << 3)];
            }
            #pragma unroll
            for (int j = 0; j < 4; ++j)
                sacc[j] = __builtin_amdgcn_mfma_f32_16x16x32_bf16(qa[s], bfr[j], sacc[j], 0, 0, 0);
        }

        // softmax (m==0 fixed shift) + packed P write into Pw (overwrites
        // P(kt-1) — already consumed above, same-wave LDS order guarantees)
        #pragma unroll
        for (int reg = 0; reg < 4; ++reg) {
            const int pr = (quad << 2) + reg;
            const float m0f = mcur[reg].x, m1f = mcur[reg].y,
                        m2f = mcur[reg].z, m3f = mcur[reg].w;
            float p[4];
            p[0] = __expf(fmaf(sacc[0][reg], scale, m0f));
            p[1] = __expf(fmaf(sacc[1][reg], scale, m1f));
            p[2] = __expf(fmaf(sacc[2][reg], scale, m2f));
            p[3] = __expf(fmaf(sacc[3][reg], scale, m3f));
            l_i[reg] += (p[0] + p[1]) + (p[2] + p[3]);
            unsigned u0 = __float_as_uint(p[0]) + 0x8000u;
            unsigned u1 = __float_as_uint(p[1]) + 0x8000u;
            unsigned u2 = __float_as_uint(p[2]) + 0x8000u;
            unsigned u3 = __float_as_uint(p[3]) + 0x8000u;
            uint2 w;
            w.x = __builtin_amdgcn_perm(u1, u0, 0x07060302u);
            w.y = __builtin_amdgcn_perm(u3, u2, 0x07060302u);
            const int e = (pr << 6) + ((((ln >> 1) ^ (pr & 7)) << 3)) + ((ln & 1) << 2);
            *(uint2*)&Pw[e] = w;
        }

        if (kt < 31) {
            #pragma unroll
            for (int reg = 0; reg < 4; ++reg)
                mcur[reg] = mnext[reg];
        }
    }

    // drain: PV(31) from Pw, Vt[1]
    #pragma unroll
    for (int s = 0; s < 2; ++s) {
        const bf16x8 a = *(const bf16x8*)&Pw[(ln << 6) + ((((s << 2) | quad) ^ (ln & 7)) << 3)];
        bf16x8 bfr[4];
        #pragma unroll
        for (int j = 0; j < 4; ++j) {
            const int r = (j << 4) + ln;
            bfr[j] = *(const bf16x8*)&Vt[1][(r << 6) + ((((s << 2) | quad) ^ (r & 7)) << 3)];
        }
        #pragma unroll
        for (int j = 0; j < 4; ++j)
            O[j] = __builtin_amdgcn_mfma_f32_16x16x32_bf16(a, bfr[j], O[j], 0, 0, 0);
    }

    #pragma unroll
    for (int reg = 0; reg < 4; ++reg) {
        float l = l_i[reg];
        l += __shfl_xor(l, 1);
        l += __shfl_xor(l, 2);
        l += __shfl_xor(l, 4);
        l += __shfl_xor(l, 8);
        const float inv = 1.0f / l;
        const int qr = q0 + (wave << 4) + (quad << 2) + reg;
        unsigned short* op = attn + (((size_t)((b_ << 11) + qr)) << 10) + (h << 6);
        #pragma unroll
        for (int j = 0; j < 4; ++j)
            op[(j << 4) + ln] = f2bf(O[j][reg] * inv);
    }
}

// =====================================================================
// Kernel 4: out = attn @ Wo^T + bo, bf16 MFMA, fp32 out.
// tau-permuted Wo staging -> float4 stores + float4 bias.
// =====================================================================
__global__ __launch_bounds__(256, 3) void out_gemm_kernel(
    const unsigned short* __restrict__ X, const unsigned short* __restrict__ W,
    const float* __restrict__ bias, float* __restrict__ out)
{
    __shared__ unsigned short As[128 * 64];
    __shared__ unsigned short Bs[128 * 64];

    const int n0 = blockIdx.x << 7;
    const int m0 = blockIdx.y << 7;
    const int tid = threadIdx.x;
    const int wave = tid >> 6, lane = tid & 63;
    const int quad = lane >> 4, ln = lane & 15;
    const int wm = (wave >> 1) << 6, wn = (wave & 1) << 6;

    const unsigned short* xptr[4];
    const unsigned short* wptr[4];
    #pragma unroll
    for (int L = 0; L < 4; ++L) {
        const int i = tid + (L << 8);
        const int r = i >> 3, cl = i & 7;
        const int cg = (cl ^ (r & 7)) << 3;
        const int rq = r & 63;
        const int tau = (r & 64) | ((rq & 15) << 2) | (rq >> 4);
        xptr[L] = X + (m0 + r) * 1024 + cg;
        wptr[L] = W + (n0 + tau) * 1024 + cg;
    }

    f32x4 acc[4][4] = {};

    for (int k0 = 0; k0 < 1024; k0 += 64) {
        #pragma unroll
        for (int L = 0; L < 4; ++L) {
            const int i = tid + (L << 8);
            gl2lds16(xptr[L] + k0, &As[i << 3]);
            gl2lds16(wptr[L] + k0, &Bs[i << 3]);
        }
        __syncthreads();
        #pragma unroll
        for (int s = 0; s < 2; ++s) {
            bf16x8 a[4], b[4];
            #pragma unroll
            for (int t = 0; t < 4; ++t) {
                const int ra = wm + (t << 4) + ln;
                a[t] = *(const bf16x8*)&As[(ra << 6) + ((((s << 2) | quad) ^ (ra & 7)) << 3)];
                const int rb = wn + (t << 4) + ln;
                b[t] = *(const bf16x8*)&Bs[(rb << 6) + ((((s << 2) | quad) ^ (rb & 7)) << 3)];
            }
            #pragma unroll
            for (int i = 0; i < 4; ++i)
                #pragma unroll
                for (int j = 0; j < 4; ++j)
                    acc[i][j] = __builtin_amdgcn_mfma_f32_16x16x32_bf16(a[i], b[j], acc[i][j], 0, 0, 0);
        }
        __syncthreads();
    }

    const float4 bv4 = *(const float4*)(bias + n0 + wn + (ln << 2));

    #pragma unroll
    for (int i = 0; i < 4; ++i)
        #pragma unroll
        for (int reg = 0; reg < 4; ++reg) {
            const int m = m0 + wm + (i << 4) + (quad << 2) + reg;
            float4 ov;
            ov.x = acc[i][0][reg] + bv4.x;
            ov.y = acc[i][1][reg] + bv4.y;
            ov.z = acc[i][2][reg] + bv4.z;
            ov.w = acc[i][3][reg] + bv4.w;
            *(float4*)(out + m * 1024 + n0 + wn + (ln << 2)) = ov;
        }
}

// =====================================================================
extern "C" void kernel_launch(void* const* d_in, const int* in_sizes, int n_in,
                              void* d_out, int out_size, void* d_ws, size_t ws_size,
                              hipStream_t stream)
{
    const float* hs   = (const float*)d_in[0];
    const float* mask = (const float*)d_in[1];
    const float* Wq   = (const float*)d_in[2];
    const float* bq   = (const float*)d_in[3];
    const float* Wk   = (const float*)d_in[4];
    const float* bk   = (const float*)d_in[5];
    const float* Wv   = (const float*)d_in[6];
    const float* bv   = (const float*)d_in[7];
    const float* Wo   = (const float*)d_in[8];
    const float* bo   = (const float*)d_in[9];

    unsigned short* ws = (unsigned short*)d_ws;
    const size_t M1 = (size_t)1 << 20;
    unsigned short* hsb   = ws;              // 4M
    unsigned short* wall  = ws + 4 * M1;     // wq|wk|wv
    unsigned short* wob   = ws + 7 * M1;
    unsigned short* qbf   = ws + 8 * M1;
    unsigned short* kbf   = ws + 12 * M1;
    unsigned short* vtb   = ws + 16 * M1;
    unsigned short* attnb = ws + 20 * M1;
    float2*         rtab  = (float2*)(ws + 24 * M1);   // 512KB

    convert_kernel<<<8448, 256, 0, stream>>>(hs, Wq, Wk, Wv, Wo, ws, rtab);
    qkv_gemm_kernel<<<dim3(24, 32), 256, 0, stream>>>(hsb, wall, bq, bk, bv, rtab, qbf, kbf, vtb);
    flash_kernel<<<1024, 256, 0, stream>>>(qbf, kbf, vtb, mask, attnb);
    out_gemm_kernel<<<dim3(8, 32), 256, 0, stream>>>(attnb, wob, bo, (float*)d_out);
}